// Round 2
// baseline (1184.462 us; speedup 1.0000x reference)
//
#include <hip/hip_runtime.h>

#define HID 128
#define NLAYER 3
#define NGRAPH 64

// ---------- degree histogram over dst (self-loop added analytically later) ----------
__global__ void k_deg(const int* __restrict__ dst, int E, int* __restrict__ deg) {
    int e = blockIdx.x * blockDim.x + threadIdx.x;
    if (e < E) atomicAdd(&deg[dst[e]], 1);
}

// ---------- dis = rsqrt(deg + 1)  (the +1 is the self-loop) ----------
__global__ void k_dis(const int* __restrict__ deg, float* __restrict__ dis, int N) {
    int n = blockIdx.x * blockDim.x + threadIdx.x;
    if (n < N) dis[n] = rsqrtf((float)deg[n] + 1.0f);
}

// ---------- single-block exclusive scan of deg -> rowptr, cursor ----------
__global__ void __launch_bounds__(1024) k_scan(const int* __restrict__ deg,
                                               int* __restrict__ rowptr,
                                               int* __restrict__ cursor, int N) {
    __shared__ int wsum[17];
    int tid = threadIdx.x;
    int lane = tid & 63, wid = tid >> 6;
    int offset = 0;
    for (int base = 0; base < N; base += 1024) {
        int i = base + tid;
        int v = (i < N) ? deg[i] : 0;
        int x = v;
        // wave-level inclusive scan
        #pragma unroll
        for (int d = 1; d < 64; d <<= 1) {
            int t = __shfl_up(x, d, 64);
            if (lane >= d) x += t;
        }
        if (lane == 63) wsum[wid] = x;
        __syncthreads();
        if (tid == 0) {
            int run = 0;
            #pragma unroll
            for (int j = 0; j < 16; ++j) { int t = wsum[j]; wsum[j] = run; run += t; }
            wsum[16] = run;
        }
        __syncthreads();
        int excl = offset + wsum[wid] + x - v;
        if (i < N) { rowptr[i] = excl; cursor[i] = excl; }
        offset += wsum[16];
        __syncthreads();   // protect wsum before next chunk overwrites it
    }
    if (tid == 0) rowptr[N] = offset;
}

// ---------- CSR fill: bucket edges by dst, precompute norm = dis[s]*dis[d] ----------
__global__ void k_fill(const int* __restrict__ src, const int* __restrict__ dst, int E,
                       const float* __restrict__ dis, int* __restrict__ cursor,
                       int* __restrict__ csrc, float* __restrict__ cnorm) {
    int e = blockIdx.x * blockDim.x + threadIdx.x;
    if (e < E) {
        int s = src[e], d = dst[e];
        int pos = atomicAdd(&cursor[d], 1);
        csrc[pos] = s;
        cnorm[pos] = dis[s] * dis[d];
    }
}

// ---------- T = A @ W   (A: [N,128], W: [128,128] staged in LDS) ----------
__global__ void __launch_bounds__(256) k_gemm(const float* __restrict__ A,
                                              const float* __restrict__ W,
                                              float* __restrict__ T, int N) {
    __shared__ float sW[HID * HID];   // 64 KiB
    for (int i = threadIdx.x; i < HID * HID / 4; i += 256)
        ((float4*)sW)[i] = ((const float4*)W)[i];
    __syncthreads();

    int c4 = (threadIdx.x & 31) * 4;     // column group: [c4, c4+4)
    int rb = threadIdx.x >> 5;           // 0..7
    int row0 = blockIdx.x * 32;
    int r0 = row0 + rb, r1 = r0 + 8, r2 = r0 + 16, r3 = r0 + 24;
    int rc0 = min(r0, N - 1), rc1 = min(r1, N - 1), rc2 = min(r2, N - 1), rc3 = min(r3, N - 1);

    const float* a0 = A + (size_t)rc0 * HID;
    const float* a1 = A + (size_t)rc1 * HID;
    const float* a2 = A + (size_t)rc2 * HID;
    const float* a3 = A + (size_t)rc3 * HID;

    float4 acc0 = {0,0,0,0}, acc1 = {0,0,0,0}, acc2 = {0,0,0,0}, acc3 = {0,0,0,0};

    #pragma unroll 4
    for (int k = 0; k < HID; k += 4) {
        float4 va0 = *(const float4*)(a0 + k);
        float4 va1 = *(const float4*)(a1 + k);
        float4 va2 = *(const float4*)(a2 + k);
        float4 va3 = *(const float4*)(a3 + k);
        #pragma unroll
        for (int kk = 0; kk < 4; ++kk) {
            float4 w = *(const float4*)&sW[(k + kk) * HID + c4];
            float e0 = (&va0.x)[kk], e1 = (&va1.x)[kk], e2 = (&va2.x)[kk], e3 = (&va3.x)[kk];
            acc0.x += e0 * w.x; acc0.y += e0 * w.y; acc0.z += e0 * w.z; acc0.w += e0 * w.w;
            acc1.x += e1 * w.x; acc1.y += e1 * w.y; acc1.z += e1 * w.z; acc1.w += e1 * w.w;
            acc2.x += e2 * w.x; acc2.y += e2 * w.y; acc2.z += e2 * w.z; acc2.w += e2 * w.w;
            acc3.x += e3 * w.x; acc3.y += e3 * w.y; acc3.z += e3 * w.z; acc3.w += e3 * w.w;
        }
    }
    if (r0 < N) *(float4*)(T + (size_t)r0 * HID + c4) = acc0;
    if (r1 < N) *(float4*)(T + (size_t)r1 * HID + c4) = acc1;
    if (r2 < N) *(float4*)(T + (size_t)r2 * HID + c4) = acc2;
    if (r3 < N) *(float4*)(T + (size_t)r3 * HID + c4) = acc3;
}

// ---------- aggregation: H[n] = relu(b + dis[n]^2 * T[n] + sum_e norm_e * T[src_e]) ----------
__global__ void __launch_bounds__(256) k_agg(const float* __restrict__ T,
                                             float* __restrict__ H,
                                             const int* __restrict__ rowptr,
                                             const int* __restrict__ csrc,
                                             const float* __restrict__ cnorm,
                                             const float* __restrict__ dis,
                                             const float* __restrict__ bias, int N) {
    int n = blockIdx.x * 2 + (threadIdx.x >> 7);
    int c = threadIdx.x & 127;
    if (n >= N) return;
    float dn = dis[n];
    float acc = bias[c] + T[(size_t)n * HID + c] * dn * dn;
    int e = rowptr[n], e1 = rowptr[n + 1];
    // 2-wide unroll: two independent gathers in flight
    for (; e + 1 < e1; e += 2) {
        int sA = csrc[e], sB = csrc[e + 1];
        float wA = cnorm[e], wB = cnorm[e + 1];
        float tA = T[(size_t)sA * HID + c];
        float tB = T[(size_t)sB * HID + c];
        acc += tA * wA + tB * wB;
    }
    if (e < e1) {
        int s = csrc[e];
        acc += T[(size_t)s * HID + c] * cnorm[e];
    }
    H[(size_t)n * HID + c] = fmaxf(acc, 0.0f);
}

// ---------- pooling: run-length local sums over sorted batch, few atomics ----------
__global__ void __launch_bounds__(128) k_pool(const float* __restrict__ H,
                                              const int* __restrict__ batch,
                                              float* __restrict__ psum,
                                              float* __restrict__ pcnt, int N) {
    int c = threadIdx.x;                 // 128 threads, one per channel
    int n0 = blockIdx.x * 128;
    int nend = min(n0 + 128, N);
    if (n0 >= N) return;
    float acc = 0.0f;
    int run = 0;
    int g = batch[n0];
    for (int n = n0; n < nend; ++n) {
        int gn = batch[n];
        if (gn != g) {
            atomicAdd(&psum[g * HID + c], acc);
            if (c == 0) atomicAdd(&pcnt[g], (float)run);
            acc = 0.0f; run = 0; g = gn;
        }
        acc += H[(size_t)n * HID + c];
        run++;
    }
    atomicAdd(&psum[g * HID + c], acc);
    if (c == 0) atomicAdd(&pcnt[g], (float)run);
}

__global__ void k_div(const float* __restrict__ psum, const float* __restrict__ pcnt,
                      float* __restrict__ out) {
    int i = blockIdx.x * blockDim.x + threadIdx.x;
    if (i < NGRAPH * HID) out[i] = psum[i] / fmaxf(pcnt[i >> 7], 1.0f);
}

extern "C" void kernel_launch(void* const* d_in, const int* in_sizes, int n_in,
                              void* d_out, int out_size, void* d_ws, size_t ws_size,
                              hipStream_t stream) {
    const float* x     = (const float*)d_in[0];
    const int*   ei    = (const int*)d_in[1];
    const int*   batch = (const int*)d_in[2];
    const float* Ws    = (const float*)d_in[3];
    const float* bs    = (const float*)d_in[4];
    float* out = (float*)d_out;

    int N = in_sizes[2];
    int E = in_sizes[1] / 2;
    const int* esrc = ei;
    const int* edst = ei + E;

    char* w = (char*)d_ws;
    auto alloc = [&](size_t bytes) {
        char* p = w;
        w += (bytes + 255) & ~(size_t)255;
        return p;
    };
    int*   deg    = (int*)  alloc((size_t)N * 4);
    float* dis    = (float*)alloc((size_t)N * 4);
    int*   rowptr = (int*)  alloc((size_t)(N + 1) * 4);
    int*   cursor = (int*)  alloc((size_t)N * 4);
    int*   csrc   = (int*)  alloc((size_t)E * 4);
    float* cnorm  = (float*)alloc((size_t)E * 4);
    float* T      = (float*)alloc((size_t)N * HID * 4);
    float* Hb     = (float*)alloc((size_t)N * HID * 4);
    float* psum   = (float*)alloc((size_t)NGRAPH * HID * 4);
    float* pcnt   = (float*)alloc((size_t)NGRAPH * 4);

    hipMemsetAsync(deg, 0, (size_t)N * 4, stream);
    hipMemsetAsync(psum, 0, (size_t)NGRAPH * HID * 4, stream);
    hipMemsetAsync(pcnt, 0, (size_t)NGRAPH * 4, stream);

    k_deg <<<(E + 255) / 256, 256, 0, stream>>>(edst, E, deg);
    k_dis <<<(N + 255) / 256, 256, 0, stream>>>(deg, dis, N);
    k_scan<<<1, 1024, 0, stream>>>(deg, rowptr, cursor, N);
    k_fill<<<(E + 255) / 256, 256, 0, stream>>>(esrc, edst, E, dis, cursor, csrc, cnorm);

    const float* hin = x;
    for (int l = 0; l < NLAYER; ++l) {
        k_gemm<<<(N + 31) / 32, 256, 0, stream>>>(hin, Ws + (size_t)l * HID * HID, T, N);
        k_agg <<<(N + 1) / 2, 256, 0, stream>>>(T, Hb, rowptr, csrc, cnorm, dis,
                                                bs + (size_t)l * HID, N);
        hin = Hb;
    }
    k_pool<<<(N + 127) / 128, 128, 0, stream>>>(Hb, batch, psum, pcnt, N);
    k_div <<<(NGRAPH * HID + 255) / 256, 256, 0, stream>>>(psum, pcnt, out);
}

// Round 3
// 926.974 us; speedup vs baseline: 1.2778x; 1.2778x over previous
//
#include <hip/hip_runtime.h>

#define HID 128
#define NLAYER 3
#define NGRAPH 64

// ---------- degree histogram over dst ----------
__global__ void k_deg(const int* __restrict__ dst, int E, int* __restrict__ deg) {
    int e = blockIdx.x * blockDim.x + threadIdx.x;
    if (e < E) atomicAdd(&deg[dst[e]], 1);
}

// ---------- dis = rsqrt(deg + 1)  (+1 = self-loop) ----------
__global__ void k_dis(const int* __restrict__ deg, float* __restrict__ dis, int N) {
    int n = blockIdx.x * blockDim.x + threadIdx.x;
    if (n < N) dis[n] = rsqrtf((float)deg[n] + 1.0f);
}

// ---------- 3-phase parallel exclusive scan of deg -> rowptr, cursor ----------
__global__ void __launch_bounds__(1024) ks_reduce(const int* __restrict__ deg,
                                                  int* __restrict__ bsum, int N) {
    __shared__ int ws[16];
    int i = blockIdx.x * 1024 + threadIdx.x;
    int v = (i < N) ? deg[i] : 0;
    #pragma unroll
    for (int d = 32; d > 0; d >>= 1) v += __shfl_down(v, d, 64);
    int lane = threadIdx.x & 63, wid = threadIdx.x >> 6;
    if (lane == 0) ws[wid] = v;
    __syncthreads();
    if (threadIdx.x == 0) {
        int s = 0;
        #pragma unroll
        for (int j = 0; j < 16; ++j) s += ws[j];
        bsum[blockIdx.x] = s;
    }
}

// single block, 128 threads: exclusive scan of block partials (nblk <= 128)
__global__ void __launch_bounds__(128) ks_scanpart(const int* __restrict__ bsum,
                                                   int* __restrict__ boff,
                                                   int* __restrict__ rowptr,
                                                   int nblk, int N) {
    __shared__ int w0sum;
    int tid = threadIdx.x;
    int v = (tid < nblk) ? bsum[tid] : 0;
    int x = v;
    #pragma unroll
    for (int d = 1; d < 64; d <<= 1) {
        int t = __shfl_up(x, d, 64);
        if ((tid & 63) >= d) x += t;
    }
    if (tid == 63) w0sum = x;
    __syncthreads();
    if (tid >= 64) x += w0sum;
    if (tid < nblk) boff[tid] = x - v;
    if (tid == nblk - 1) rowptr[N] = x;
}

__global__ void __launch_bounds__(1024) ks_apply(const int* __restrict__ deg,
                                                 const int* __restrict__ boff,
                                                 int* __restrict__ rowptr,
                                                 int* __restrict__ cursor, int N) {
    __shared__ int wsum[17];
    int tid = threadIdx.x;
    int lane = tid & 63, wid = tid >> 6;
    int i = blockIdx.x * 1024 + tid;
    int v = (i < N) ? deg[i] : 0;
    int x = v;
    #pragma unroll
    for (int d = 1; d < 64; d <<= 1) {
        int t = __shfl_up(x, d, 64);
        if (lane >= d) x += t;
    }
    if (lane == 63) wsum[wid] = x;
    __syncthreads();
    if (tid == 0) {
        int run = 0;
        #pragma unroll
        for (int j = 0; j < 16; ++j) { int t = wsum[j]; wsum[j] = run; run += t; }
    }
    __syncthreads();
    if (i < N) {
        int excl = boff[blockIdx.x] + wsum[wid] + x - v;
        rowptr[i] = excl;
        cursor[i] = excl;
    }
}

// ---------- CSR fill: bucket src ids by dst (norm folded away) ----------
__global__ void k_fill(const int* __restrict__ src, const int* __restrict__ dst, int E,
                       int* __restrict__ cursor, int* __restrict__ csrc) {
    int e = blockIdx.x * blockDim.x + threadIdx.x;
    if (e < E) {
        int pos = atomicAdd(&cursor[dst[e]], 1);
        csrc[pos] = src[e];
    }
}

// ---------- T' = dis[n] * (A @ W)[n]   (W staged in LDS) ----------
__global__ void __launch_bounds__(256) k_gemm(const float* __restrict__ A,
                                              const float* __restrict__ W,
                                              const float* __restrict__ dis,
                                              float* __restrict__ T, int N) {
    __shared__ float sW[HID * HID];   // 64 KiB
    for (int i = threadIdx.x; i < HID * HID / 4; i += 256)
        ((float4*)sW)[i] = ((const float4*)W)[i];
    __syncthreads();

    int c4 = (threadIdx.x & 31) * 4;
    int rb = threadIdx.x >> 5;           // 0..7
    int row0 = blockIdx.x * 32;
    int r0 = row0 + rb, r1 = r0 + 8, r2 = r0 + 16, r3 = r0 + 24;
    int rc0 = min(r0, N - 1), rc1 = min(r1, N - 1), rc2 = min(r2, N - 1), rc3 = min(r3, N - 1);

    const float* a0 = A + (size_t)rc0 * HID;
    const float* a1 = A + (size_t)rc1 * HID;
    const float* a2 = A + (size_t)rc2 * HID;
    const float* a3 = A + (size_t)rc3 * HID;

    float4 acc0 = {0,0,0,0}, acc1 = {0,0,0,0}, acc2 = {0,0,0,0}, acc3 = {0,0,0,0};

    #pragma unroll 4
    for (int k = 0; k < HID; k += 4) {
        float4 va0 = *(const float4*)(a0 + k);
        float4 va1 = *(const float4*)(a1 + k);
        float4 va2 = *(const float4*)(a2 + k);
        float4 va3 = *(const float4*)(a3 + k);
        #pragma unroll
        for (int kk = 0; kk < 4; ++kk) {
            float4 w = *(const float4*)&sW[(k + kk) * HID + c4];
            float e0 = (&va0.x)[kk], e1 = (&va1.x)[kk], e2 = (&va2.x)[kk], e3 = (&va3.x)[kk];
            acc0.x += e0 * w.x; acc0.y += e0 * w.y; acc0.z += e0 * w.z; acc0.w += e0 * w.w;
            acc1.x += e1 * w.x; acc1.y += e1 * w.y; acc1.z += e1 * w.z; acc1.w += e1 * w.w;
            acc2.x += e2 * w.x; acc2.y += e2 * w.y; acc2.z += e2 * w.z; acc2.w += e2 * w.w;
            acc3.x += e3 * w.x; acc3.y += e3 * w.y; acc3.z += e3 * w.z; acc3.w += e3 * w.w;
        }
    }
    if (r0 < N) {
        float d = dis[r0];
        acc0.x *= d; acc0.y *= d; acc0.z *= d; acc0.w *= d;
        *(float4*)(T + (size_t)r0 * HID + c4) = acc0;
    }
    if (r1 < N) {
        float d = dis[r1];
        acc1.x *= d; acc1.y *= d; acc1.z *= d; acc1.w *= d;
        *(float4*)(T + (size_t)r1 * HID + c4) = acc1;
    }
    if (r2 < N) {
        float d = dis[r2];
        acc2.x *= d; acc2.y *= d; acc2.z *= d; acc2.w *= d;
        *(float4*)(T + (size_t)r2 * HID + c4) = acc2;
    }
    if (r3 < N) {
        float d = dis[r3];
        acc3.x *= d; acc3.y *= d; acc3.z *= d; acc3.w *= d;
        *(float4*)(T + (size_t)r3 * HID + c4) = acc3;
    }
}

// ---------- aggregation: one wave per node, float2/lane (512B row per instr) ----------
// H[n] = relu(bias + dis[n] * (T'[n] + sum_e T'[src_e]))
__global__ void __launch_bounds__(256) k_agg(const float* __restrict__ Tp,
                                             float* __restrict__ H,
                                             const int* __restrict__ rowptr,
                                             const int* __restrict__ csrc,
                                             const float* __restrict__ dis,
                                             const float* __restrict__ bias, int N) {
    int n = blockIdx.x * 4 + (threadIdx.x >> 6);
    int lane = threadIdx.x & 63;
    if (n >= N) return;

    const float2* base = (const float2*)Tp;
    float2 acc = base[(size_t)n * 64 + lane];   // self term
    int e = rowptr[n], e1 = rowptr[n + 1];

    // 4 independent row-gathers in flight
    for (; e + 3 < e1; e += 4) {
        int s0 = csrc[e], s1 = csrc[e + 1], s2 = csrc[e + 2], s3 = csrc[e + 3];
        float2 v0 = base[(size_t)s0 * 64 + lane];
        float2 v1 = base[(size_t)s1 * 64 + lane];
        float2 v2 = base[(size_t)s2 * 64 + lane];
        float2 v3 = base[(size_t)s3 * 64 + lane];
        acc.x += v0.x + v1.x + v2.x + v3.x;
        acc.y += v0.y + v1.y + v2.y + v3.y;
    }
    for (; e < e1; ++e) {
        int s = csrc[e];
        float2 v = base[(size_t)s * 64 + lane];
        acc.x += v.x; acc.y += v.y;
    }

    float dn = dis[n];
    float2 b2 = ((const float2*)bias)[lane];
    float2 r;
    r.x = fmaxf(b2.x + dn * acc.x, 0.0f);
    r.y = fmaxf(b2.y + dn * acc.y, 0.0f);
    ((float2*)H)[(size_t)n * 64 + lane] = r;
}

// ---------- pooling: run-length local sums, 2 interleaved row groups ----------
__global__ void __launch_bounds__(256) k_pool(const float* __restrict__ H,
                                              const int* __restrict__ batch,
                                              float* __restrict__ psum,
                                              float* __restrict__ pcnt, int N) {
    int grp = threadIdx.x >> 7;          // 0/1: alternate rows
    int c = threadIdx.x & 127;
    int n0 = blockIdx.x * 128;
    if (n0 >= N) return;
    int nend = min(n0 + 128, N);
    float acc = 0.0f;
    int run = 0, g = -1;
    for (int n = n0 + grp; n < nend; n += 2) {
        int gn = batch[n];
        if (gn != g) {
            if (run) {
                atomicAdd(&psum[g * HID + c], acc);
                if (c == 0) atomicAdd(&pcnt[g], (float)run);
            }
            acc = 0.0f; run = 0; g = gn;
        }
        acc += H[(size_t)n * HID + c];
        run++;
    }
    if (run) {
        atomicAdd(&psum[g * HID + c], acc);
        if (c == 0) atomicAdd(&pcnt[g], (float)run);
    }
}

__global__ void k_div(const float* __restrict__ psum, const float* __restrict__ pcnt,
                      float* __restrict__ out) {
    int i = blockIdx.x * blockDim.x + threadIdx.x;
    if (i < NGRAPH * HID) out[i] = psum[i] / fmaxf(pcnt[i >> 7], 1.0f);
}

extern "C" void kernel_launch(void* const* d_in, const int* in_sizes, int n_in,
                              void* d_out, int out_size, void* d_ws, size_t ws_size,
                              hipStream_t stream) {
    const float* x     = (const float*)d_in[0];
    const int*   ei    = (const int*)d_in[1];
    const int*   batch = (const int*)d_in[2];
    const float* Ws    = (const float*)d_in[3];
    const float* bs    = (const float*)d_in[4];
    float* out = (float*)d_out;

    int N = in_sizes[2];
    int E = in_sizes[1] / 2;
    const int* esrc = ei;
    const int* edst = ei + E;
    int nblk = (N + 1023) / 1024;        // <= 128 for N <= 131072

    char* w = (char*)d_ws;
    auto alloc = [&](size_t bytes) {
        char* p = w;
        w += (bytes + 255) & ~(size_t)255;
        return p;
    };
    int*   deg    = (int*)  alloc((size_t)N * 4);
    float* dis    = (float*)alloc((size_t)N * 4);
    int*   rowptr = (int*)  alloc((size_t)(N + 1) * 4);
    int*   cursor = (int*)  alloc((size_t)N * 4);
    int*   bsum   = (int*)  alloc(128 * 4);
    int*   boff   = (int*)  alloc(128 * 4);
    int*   csrc   = (int*)  alloc((size_t)E * 4);
    float* T      = (float*)alloc((size_t)N * HID * 4);
    float* Hb     = (float*)alloc((size_t)N * HID * 4);
    float* psum   = (float*)alloc((size_t)NGRAPH * HID * 4);
    float* pcnt   = (float*)alloc((size_t)NGRAPH * 4);

    hipMemsetAsync(deg, 0, (size_t)N * 4, stream);
    hipMemsetAsync(psum, 0, (size_t)NGRAPH * HID * 4, stream);
    hipMemsetAsync(pcnt, 0, (size_t)NGRAPH * 4, stream);

    k_deg      <<<(E + 255) / 256, 256, 0, stream>>>(edst, E, deg);
    k_dis      <<<(N + 255) / 256, 256, 0, stream>>>(deg, dis, N);
    ks_reduce  <<<nblk, 1024, 0, stream>>>(deg, bsum, N);
    ks_scanpart<<<1, 128, 0, stream>>>(bsum, boff, rowptr, nblk, N);
    ks_apply   <<<nblk, 1024, 0, stream>>>(deg, boff, rowptr, cursor, N);
    k_fill     <<<(E + 255) / 256, 256, 0, stream>>>(esrc, edst, E, cursor, csrc);

    const float* hin = x;
    for (int l = 0; l < NLAYER; ++l) {
        k_gemm<<<(N + 31) / 32, 256, 0, stream>>>(hin, Ws + (size_t)l * HID * HID, dis, T, N);
        k_agg <<<(N + 3) / 4, 256, 0, stream>>>(T, Hb, rowptr, csrc, dis,
                                                bs + (size_t)l * HID, N);
        hin = Hb;
    }
    k_pool<<<(N + 127) / 128, 256, 0, stream>>>(Hb, batch, psum, pcnt, N);
    k_div <<<(NGRAPH * HID + 255) / 256, 256, 0, stream>>>(psum, pcnt, out);
}

// Round 6
// 878.776 us; speedup vs baseline: 1.3479x; 1.0548x over previous
//
#include <hip/hip_runtime.h>

#define HID 128
#define NLAYER 3
#define NGRAPH 64
#define NPART 8          // one dst-range per XCD (blockIdx % 8 ~ XCD round-robin)

// ---------- degree histogram, XCD-partitioned by dst range ----------
__global__ void __launch_bounds__(256) k_deg(const int* __restrict__ dst, int E,
                                             int* __restrict__ deg, int N) {
    int part = blockIdx.x & (NPART - 1);
    int grp  = blockIdx.x >> 3;
    int ngrp = gridDim.x >> 3;
    int lo = (int)((long long)part * N / NPART);
    int hi = (int)((long long)(part + 1) * N / NPART);
    for (int e = grp * 256 + threadIdx.x; e < E; e += ngrp * 256) {
        int d = dst[e];
        if (d >= lo && d < hi) atomicAdd(&deg[d], 1);
    }
}

// ---------- 3-phase parallel exclusive scan of deg -> rowptr, cursor, dis ----------
__global__ void __launch_bounds__(1024) ks_reduce(const int* __restrict__ deg,
                                                  int* __restrict__ bsum, int N) {
    __shared__ int ws[16];
    int i = blockIdx.x * 1024 + threadIdx.x;
    int v = (i < N) ? deg[i] : 0;
    #pragma unroll
    for (int d = 32; d > 0; d >>= 1) v += __shfl_down(v, d, 64);
    int lane = threadIdx.x & 63, wid = threadIdx.x >> 6;
    if (lane == 0) ws[wid] = v;
    __syncthreads();
    if (threadIdx.x == 0) {
        int s = 0;
        #pragma unroll
        for (int j = 0; j < 16; ++j) s += ws[j];
        bsum[blockIdx.x] = s;
    }
}

__global__ void __launch_bounds__(128) ks_scanpart(const int* __restrict__ bsum,
                                                   int* __restrict__ boff,
                                                   int* __restrict__ rowptr,
                                                   int nblk, int N) {
    __shared__ int w0sum;
    int tid = threadIdx.x;
    int v = (tid < nblk) ? bsum[tid] : 0;
    int x = v;
    #pragma unroll
    for (int d = 1; d < 64; d <<= 1) {
        int t = __shfl_up(x, d, 64);
        if ((tid & 63) >= d) x += t;
    }
    if (tid == 63) w0sum = x;
    __syncthreads();
    if (tid >= 64) x += w0sum;
    if (tid < nblk) boff[tid] = x - v;
    if (tid == nblk - 1) rowptr[N] = x;
}

__global__ void __launch_bounds__(1024) ks_apply(const int* __restrict__ deg,
                                                 const int* __restrict__ boff,
                                                 int* __restrict__ rowptr,
                                                 int* __restrict__ cursor,
                                                 float* __restrict__ dis, int N) {
    __shared__ int wsum[17];
    int tid = threadIdx.x;
    int lane = tid & 63, wid = tid >> 6;
    int i = blockIdx.x * 1024 + tid;
    int v = (i < N) ? deg[i] : 0;
    int x = v;
    #pragma unroll
    for (int d = 1; d < 64; d <<= 1) {
        int t = __shfl_up(x, d, 64);
        if (lane >= d) x += t;
    }
    if (lane == 63) wsum[wid] = x;
    __syncthreads();
    if (tid == 0) {
        int run = 0;
        #pragma unroll
        for (int j = 0; j < 16; ++j) { int t = wsum[j]; wsum[j] = run; run += t; }
    }
    __syncthreads();
    if (i < N) {
        int excl = boff[blockIdx.x] + wsum[wid] + x - v;
        rowptr[i] = excl;
        cursor[i] = excl;
        dis[i] = rsqrtf((float)v + 1.0f);   // +1 = self-loop
    }
}

// ---------- CSR fill, XCD-partitioned by dst range ----------
__global__ void __launch_bounds__(256) k_fill(const int* __restrict__ src,
                                              const int* __restrict__ dst, int E,
                                              int* __restrict__ cursor,
                                              int* __restrict__ csrc, int N) {
    int part = blockIdx.x & (NPART - 1);
    int grp  = blockIdx.x >> 3;
    int ngrp = gridDim.x >> 3;
    int lo = (int)((long long)part * N / NPART);
    int hi = (int)((long long)(part + 1) * N / NPART);
    for (int e = grp * 256 + threadIdx.x; e < E; e += ngrp * 256) {
        int d = dst[e];
        if (d >= lo && d < hi) {
            int pos = atomicAdd(&cursor[d], 1);
            csrc[pos] = src[e];
        }
    }
}

// ---------- T' = dis[n] * (A @ W)[n]   (W staged in LDS) ----------
__global__ void __launch_bounds__(256) k_gemm(const float* __restrict__ A,
                                              const float* __restrict__ W,
                                              const float* __restrict__ dis,
                                              float* __restrict__ T, int N) {
    __shared__ float sW[HID * HID];   // 64 KiB
    for (int i = threadIdx.x; i < HID * HID / 4; i += 256)
        ((float4*)sW)[i] = ((const float4*)W)[i];
    __syncthreads();

    int c4 = (threadIdx.x & 31) * 4;
    int rb = threadIdx.x >> 5;           // 0..7
    int row0 = blockIdx.x * 32;
    int r0 = row0 + rb, r1 = r0 + 8, r2 = r0 + 16, r3 = r0 + 24;
    int rc0 = min(r0, N - 1), rc1 = min(r1, N - 1), rc2 = min(r2, N - 1), rc3 = min(r3, N - 1);

    const float* a0 = A + (size_t)rc0 * HID;
    const float* a1 = A + (size_t)rc1 * HID;
    const float* a2 = A + (size_t)rc2 * HID;
    const float* a3 = A + (size_t)rc3 * HID;

    float4 acc0 = {0,0,0,0}, acc1 = {0,0,0,0}, acc2 = {0,0,0,0}, acc3 = {0,0,0,0};

    #pragma unroll 4
    for (int k = 0; k < HID; k += 4) {
        float4 va0 = *(const float4*)(a0 + k);
        float4 va1 = *(const float4*)(a1 + k);
        float4 va2 = *(const float4*)(a2 + k);
        float4 va3 = *(const float4*)(a3 + k);
        #pragma unroll
        for (int kk = 0; kk < 4; ++kk) {
            float4 w = *(const float4*)&sW[(k + kk) * HID + c4];
            float e0 = (&va0.x)[kk], e1 = (&va1.x)[kk], e2 = (&va2.x)[kk], e3 = (&va3.x)[kk];
            acc0.x += e0 * w.x; acc0.y += e0 * w.y; acc0.z += e0 * w.z; acc0.w += e0 * w.w;
            acc1.x += e1 * w.x; acc1.y += e1 * w.y; acc1.z += e1 * w.z; acc1.w += e1 * w.w;
            acc2.x += e2 * w.x; acc2.y += e2 * w.y; acc2.z += e2 * w.z; acc2.w += e2 * w.w;
            acc3.x += e3 * w.x; acc3.y += e3 * w.y; acc3.z += e3 * w.z; acc3.w += e3 * w.w;
        }
    }
    if (r0 < N) {
        float d = dis[r0];
        acc0.x *= d; acc0.y *= d; acc0.z *= d; acc0.w *= d;
        *(float4*)(T + (size_t)r0 * HID + c4) = acc0;
    }
    if (r1 < N) {
        float d = dis[r1];
        acc1.x *= d; acc1.y *= d; acc1.z *= d; acc1.w *= d;
        *(float4*)(T + (size_t)r1 * HID + c4) = acc1;
    }
    if (r2 < N) {
        float d = dis[r2];
        acc2.x *= d; acc2.y *= d; acc2.z *= d; acc2.w *= d;
        *(float4*)(T + (size_t)r2 * HID + c4) = acc2;
    }
    if (r3 < N) {
        float d = dis[r3];
        acc3.x *= d; acc3.y *= d; acc3.z *= d; acc3.w *= d;
        *(float4*)(T + (size_t)r3 * HID + c4) = acc3;
    }
}

// ---------- aggregation: one wave per node, float2/lane, 8 gathers in flight ----------
// H[n] = relu(bias + dis[n] * (T'[n] + sum_e T'[src_e]))
__global__ void __launch_bounds__(256) k_agg(const float* __restrict__ Tp,
                                             float* __restrict__ H,
                                             const int* __restrict__ rowptr,
                                             const int* __restrict__ csrc,
                                             const float* __restrict__ dis,
                                             const float* __restrict__ bias, int N) {
    int n = blockIdx.x * 4 + (threadIdx.x >> 6);
    int lane = threadIdx.x & 63;
    if (n >= N) return;

    const float2* base = (const float2*)Tp;
    float2 acc = base[(size_t)n * 64 + lane];   // self term
    float2 acc2 = {0.0f, 0.0f};
    int e = rowptr[n], e1 = rowptr[n + 1];

    for (; e + 7 < e1; e += 8) {
        int s0 = csrc[e],     s1 = csrc[e + 1], s2 = csrc[e + 2], s3 = csrc[e + 3];
        int s4 = csrc[e + 4], s5 = csrc[e + 5], s6 = csrc[e + 6], s7 = csrc[e + 7];
        float2 v0 = base[(size_t)s0 * 64 + lane];
        float2 v1 = base[(size_t)s1 * 64 + lane];
        float2 v2 = base[(size_t)s2 * 64 + lane];
        float2 v3 = base[(size_t)s3 * 64 + lane];
        float2 v4 = base[(size_t)s4 * 64 + lane];
        float2 v5 = base[(size_t)s5 * 64 + lane];
        float2 v6 = base[(size_t)s6 * 64 + lane];
        float2 v7 = base[(size_t)s7 * 64 + lane];
        acc.x  += v0.x + v1.x + v2.x + v3.x;
        acc.y  += v0.y + v1.y + v2.y + v3.y;
        acc2.x += v4.x + v5.x + v6.x + v7.x;
        acc2.y += v4.y + v5.y + v6.y + v7.y;
    }
    for (; e + 1 < e1; e += 2) {
        int s0 = csrc[e], s1 = csrc[e + 1];
        float2 v0 = base[(size_t)s0 * 64 + lane];
        float2 v1 = base[(size_t)s1 * 64 + lane];
        acc.x += v0.x + v1.x;
        acc.y += v0.y + v1.y;
    }
    if (e < e1) {
        int s = csrc[e];
        float2 v = base[(size_t)s * 64 + lane];
        acc.x += v.x; acc.y += v.y;
    }
    acc.x += acc2.x; acc.y += acc2.y;

    float dn = dis[n];
    float2 b2 = ((const float2*)bias)[lane];
    float2 r;
    r.x = fmaxf(b2.x + dn * acc.x, 0.0f);
    r.y = fmaxf(b2.y + dn * acc.y, 0.0f);
    ((float2*)H)[(size_t)n * 64 + lane] = r;
}

// ---------- pooling: run-length local sums, 2 interleaved row groups ----------
__global__ void __launch_bounds__(256) k_pool(const float* __restrict__ H,
                                              const int* __restrict__ batch,
                                              float* __restrict__ psum,
                                              float* __restrict__ pcnt, int N) {
    int grp = threadIdx.x >> 7;          // 0/1: alternate rows
    int c = threadIdx.x & 127;
    int n0 = blockIdx.x * 128;
    if (n0 >= N) return;
    int nend = min(n0 + 128, N);
    float acc = 0.0f;
    int run = 0, g = -1;
    for (int n = n0 + grp; n < nend; n += 2) {
        int gn = batch[n];
        if (gn != g) {
            if (run) {
                atomicAdd(&psum[g * HID + c], acc);
                if (c == 0) atomicAdd(&pcnt[g], (float)run);
            }
            acc = 0.0f; run = 0; g = gn;
        }
        acc += H[(size_t)n * HID + c];
        run++;
    }
    if (run) {
        atomicAdd(&psum[g * HID + c], acc);
        if (c == 0) atomicAdd(&pcnt[g], (float)run);
    }
}

__global__ void k_div(const float* __restrict__ psum, const float* __restrict__ pcnt,
                      float* __restrict__ out) {
    int i = blockIdx.x * blockDim.x + threadIdx.x;
    if (i < NGRAPH * HID) out[i] = psum[i] / fmaxf(pcnt[i >> 7], 1.0f);
}

extern "C" void kernel_launch(void* const* d_in, const int* in_sizes, int n_in,
                              void* d_out, int out_size, void* d_ws, size_t ws_size,
                              hipStream_t stream) {
    const float* x     = (const float*)d_in[0];
    const int*   ei    = (const int*)d_in[1];
    const int*   batch = (const int*)d_in[2];
    const float* Ws    = (const float*)d_in[3];
    const float* bs    = (const float*)d_in[4];
    float* out = (float*)d_out;

    int N = in_sizes[2];
    int E = in_sizes[1] / 2;
    const int* esrc = ei;
    const int* edst = ei + E;
    int nblk = (N + 1023) / 1024;        // <= 128 for N <= 131072

    char* w = (char*)d_ws;
    auto alloc = [&](size_t bytes) {
        char* p = w;
        w += (bytes + 255) & ~(size_t)255;
        return p;
    };
    int*   deg    = (int*)  alloc((size_t)N * 4);
    float* dis    = (float*)alloc((size_t)N * 4);
    int*   rowptr = (int*)  alloc((size_t)(N + 1) * 4);
    int*   cursor = (int*)  alloc((size_t)N * 4);
    int*   bsum   = (int*)  alloc(128 * 4);
    int*   boff   = (int*)  alloc(128 * 4);
    int*   csrc   = (int*)  alloc((size_t)E * 4);
    float* T      = (float*)alloc((size_t)N * HID * 4);
    float* Hb     = (float*)alloc((size_t)N * HID * 4);
    float* psum   = (float*)alloc((size_t)NGRAPH * HID * 4);
    float* pcnt   = (float*)alloc((size_t)NGRAPH * 4);

    hipMemsetAsync(deg, 0, (size_t)N * 4, stream);
    hipMemsetAsync(psum, 0, (size_t)NGRAPH * HID * 4, stream);
    hipMemsetAsync(pcnt, 0, (size_t)NGRAPH * 4, stream);

    k_deg      <<<2048, 256, 0, stream>>>(edst, E, deg, N);
    ks_reduce  <<<nblk, 1024, 0, stream>>>(deg, bsum, N);
    ks_scanpart<<<1, 128, 0, stream>>>(bsum, boff, rowptr, nblk, N);
    ks_apply   <<<nblk, 1024, 0, stream>>>(deg, boff, rowptr, cursor, dis, N);
    k_fill     <<<2048, 256, 0, stream>>>(esrc, edst, E, cursor, csrc, N);

    const float* hin = x;
    for (int l = 0; l < NLAYER; ++l) {
        k_gemm<<<(N + 31) / 32, 256, 0, stream>>>(hin, Ws + (size_t)l * HID * HID, dis, T, N);
        k_agg <<<(N + 3) / 4, 256, 0, stream>>>(T, Hb, rowptr, csrc, dis,
                                                bs + (size_t)l * HID, N);
        hin = Hb;
    }
    k_pool<<<(N + 127) / 128, 256, 0, stream>>>(Hb, batch, psum, pcnt, N);
    k_div <<<(NGRAPH * HID + 255) / 256, 256, 0, stream>>>(psum, pcnt, out);
}

// Round 12
// 702.867 us; speedup vs baseline: 1.6852x; 1.2503x over previous
//
#include <hip/hip_runtime.h>
#include <hip/hip_fp16.h>

#define HID 128
#define NLAYER 3
#define NGRAPH 64
#define NPART 8          // one dst-range per XCD (blockIdx % 8 ~ XCD round-robin)

// ---------- degree histogram, XCD-partitioned by dst range ----------
__global__ void __launch_bounds__(256) k_deg(const int* __restrict__ dst, int E,
                                             int* __restrict__ deg, int N) {
    int part = blockIdx.x & (NPART - 1);
    int grp  = blockIdx.x >> 3;
    int ngrp = gridDim.x >> 3;
    int lo = (int)((long long)part * N / NPART);
    int hi = (int)((long long)(part + 1) * N / NPART);
    for (int e = grp * 256 + threadIdx.x; e < E; e += ngrp * 256) {
        int d = dst[e];
        if (d >= lo && d < hi) atomicAdd(&deg[d], 1);
    }
}

// ---------- 3-phase parallel exclusive scan of deg -> rowptr, cursor, dis ----------
__global__ void __launch_bounds__(1024) ks_reduce(const int* __restrict__ deg,
                                                  int* __restrict__ bsum, int N) {
    __shared__ int ws[16];
    int i = blockIdx.x * 1024 + threadIdx.x;
    int v = (i < N) ? deg[i] : 0;
    #pragma unroll
    for (int d = 32; d > 0; d >>= 1) v += __shfl_down(v, d, 64);
    int lane = threadIdx.x & 63, wid = threadIdx.x >> 6;
    if (lane == 0) ws[wid] = v;
    __syncthreads();
    if (threadIdx.x == 0) {
        int s = 0;
        #pragma unroll
        for (int j = 0; j < 16; ++j) s += ws[j];
        bsum[blockIdx.x] = s;
    }
}

__global__ void __launch_bounds__(128) ks_scanpart(const int* __restrict__ bsum,
                                                   int* __restrict__ boff,
                                                   int* __restrict__ rowptr,
                                                   int nblk, int N) {
    __shared__ int w0sum;
    int tid = threadIdx.x;
    int v = (tid < nblk) ? bsum[tid] : 0;
    int x = v;
    #pragma unroll
    for (int d = 1; d < 64; d <<= 1) {
        int t = __shfl_up(x, d, 64);
        if ((tid & 63) >= d) x += t;
    }
    if (tid == 63) w0sum = x;
    __syncthreads();
    if (tid >= 64) x += w0sum;
    if (tid < nblk) boff[tid] = x - v;
    if (tid == nblk - 1) rowptr[N] = x;
}

__global__ void __launch_bounds__(1024) ks_apply(const int* __restrict__ deg,
                                                 const int* __restrict__ boff,
                                                 int* __restrict__ rowptr,
                                                 int* __restrict__ cursor,
                                                 float* __restrict__ dis, int N) {
    __shared__ int wsum[17];
    int tid = threadIdx.x;
    int lane = tid & 63, wid = tid >> 6;
    int i = blockIdx.x * 1024 + tid;
    int v = (i < N) ? deg[i] : 0;
    int x = v;
    #pragma unroll
    for (int d = 1; d < 64; d <<= 1) {
        int t = __shfl_up(x, d, 64);
        if (lane >= d) x += t;
    }
    if (lane == 63) wsum[wid] = x;
    __syncthreads();
    if (tid == 0) {
        int run = 0;
        #pragma unroll
        for (int j = 0; j < 16; ++j) { int t = wsum[j]; wsum[j] = run; run += t; }
    }
    __syncthreads();
    if (i < N) {
        int excl = boff[blockIdx.x] + wsum[wid] + x - v;
        rowptr[i] = excl;
        cursor[i] = excl;
        dis[i] = rsqrtf((float)v + 1.0f);   // +1 = self-loop
    }
}

// ---------- CSR fill, XCD-partitioned by dst range ----------
__global__ void __launch_bounds__(256) k_fill(const int* __restrict__ src,
                                              const int* __restrict__ dst, int E,
                                              int* __restrict__ cursor,
                                              int* __restrict__ csrc, int N) {
    int part = blockIdx.x & (NPART - 1);
    int grp  = blockIdx.x >> 3;
    int ngrp = gridDim.x >> 3;
    int lo = (int)((long long)part * N / NPART);
    int hi = (int)((long long)(part + 1) * N / NPART);
    for (int e = grp * 256 + threadIdx.x; e < E; e += ngrp * 256) {
        int d = dst[e];
        if (d >= lo && d < hi) {
            int pos = atomicAdd(&cursor[d], 1);
            csrc[pos] = src[e];
        }
    }
}

// ---------- T' = fp16( dis[n] * (A @ W)[n] )  (W staged in LDS, 8 rows/thread) ----------
__global__ void __launch_bounds__(256) k_gemm(const float* __restrict__ A,
                                              const float* __restrict__ W,
                                              const float* __restrict__ dis,
                                              __half* __restrict__ T, int N) {
    __shared__ float sW[HID * HID];   // 64 KiB
    for (int i = threadIdx.x; i < HID * HID / 4; i += 256)
        ((float4*)sW)[i] = ((const float4*)W)[i];
    __syncthreads();

    int c4 = (threadIdx.x & 31) * 4;     // 4 output cols
    int rb = threadIdx.x >> 5;           // 0..7
    int row0 = blockIdx.x * 64;

    int r[8]; const float* a[8];
    #pragma unroll
    for (int j = 0; j < 8; ++j) {
        r[j] = row0 + rb + 8 * j;
        a[j] = A + (size_t)min(r[j], N - 1) * HID;
    }

    float4 acc[8];
    #pragma unroll
    for (int j = 0; j < 8; ++j) acc[j] = float4{0, 0, 0, 0};

    for (int k = 0; k < HID; k += 4) {
        float4 va[8];
        #pragma unroll
        for (int j = 0; j < 8; ++j) va[j] = *(const float4*)(a[j] + k);
        #pragma unroll
        for (int kk = 0; kk < 4; ++kk) {
            float4 w = *(const float4*)&sW[(k + kk) * HID + c4];
            #pragma unroll
            for (int j = 0; j < 8; ++j) {
                float e = (&va[j].x)[kk];
                acc[j].x += e * w.x; acc[j].y += e * w.y;
                acc[j].z += e * w.z; acc[j].w += e * w.w;
            }
        }
    }
    #pragma unroll
    for (int j = 0; j < 8; ++j) {
        if (r[j] < N) {
            float d = dis[r[j]];
            ushort4 u;
            u.x = __half_as_ushort(__float2half_rn(acc[j].x * d));
            u.y = __half_as_ushort(__float2half_rn(acc[j].y * d));
            u.z = __half_as_ushort(__float2half_rn(acc[j].z * d));
            u.w = __half_as_ushort(__float2half_rn(acc[j].w * d));
            *(ushort4*)((unsigned short*)T + (size_t)r[j] * HID + c4) = u;
        }
    }
}

// ---------- aggregation: one wave per node, half2/lane (256B row per instr) ----------
// H[n] = relu(bias + dis[n] * (T'[n] + sum_e T'[src_e]))
__global__ void __launch_bounds__(256) k_agg(const __half* __restrict__ Tp,
                                             float* __restrict__ H,
                                             const int* __restrict__ rowptr,
                                             const int* __restrict__ csrc,
                                             const float* __restrict__ dis,
                                             const float* __restrict__ bias, int N) {
    int n = blockIdx.x * 4 + (threadIdx.x >> 6);
    int lane = threadIdx.x & 63;
    if (n >= N) return;

    const __half2* base = (const __half2*)Tp;   // row stride = 64 half2
    float2 selfv = __half22float2(base[(size_t)n * 64 + lane]);
    float2 acc  = selfv;
    float2 acc2 = {0.0f, 0.0f};
    int e = rowptr[n], e1 = rowptr[n + 1];

    for (; e + 7 < e1; e += 8) {
        int s0 = csrc[e],     s1 = csrc[e + 1], s2 = csrc[e + 2], s3 = csrc[e + 3];
        int s4 = csrc[e + 4], s5 = csrc[e + 5], s6 = csrc[e + 6], s7 = csrc[e + 7];
        __half2 h0 = base[(size_t)s0 * 64 + lane];
        __half2 h1 = base[(size_t)s1 * 64 + lane];
        __half2 h2 = base[(size_t)s2 * 64 + lane];
        __half2 h3 = base[(size_t)s3 * 64 + lane];
        __half2 h4 = base[(size_t)s4 * 64 + lane];
        __half2 h5 = base[(size_t)s5 * 64 + lane];
        __half2 h6 = base[(size_t)s6 * 64 + lane];
        __half2 h7 = base[(size_t)s7 * 64 + lane];
        float2 v0 = __half22float2(h0), v1 = __half22float2(h1);
        float2 v2 = __half22float2(h2), v3 = __half22float2(h3);
        float2 v4 = __half22float2(h4), v5 = __half22float2(h5);
        float2 v6 = __half22float2(h6), v7 = __half22float2(h7);
        acc.x  += v0.x + v1.x + v2.x + v3.x;
        acc.y  += v0.y + v1.y + v2.y + v3.y;
        acc2.x += v4.x + v5.x + v6.x + v7.x;
        acc2.y += v4.y + v5.y + v6.y + v7.y;
    }
    for (; e + 1 < e1; e += 2) {
        int s0 = csrc[e], s1 = csrc[e + 1];
        float2 v0 = __half22float2(base[(size_t)s0 * 64 + lane]);
        float2 v1 = __half22float2(base[(size_t)s1 * 64 + lane]);
        acc.x += v0.x + v1.x;
        acc.y += v0.y + v1.y;
    }
    if (e < e1) {
        float2 v = __half22float2(base[(size_t)csrc[e] * 64 + lane]);
        acc.x += v.x; acc.y += v.y;
    }
    acc.x += acc2.x; acc.y += acc2.y;

    float dn = dis[n];
    float2 b2 = ((const float2*)bias)[lane];
    float2 rr;
    rr.x = fmaxf(b2.x + dn * acc.x, 0.0f);
    rr.y = fmaxf(b2.y + dn * acc.y, 0.0f);
    ((float2*)H)[(size_t)n * 64 + lane] = rr;
}

// ---------- pooling: run-length local sums, 2 interleaved row groups ----------
__global__ void __launch_bounds__(256) k_pool(const float* __restrict__ H,
                                              const int* __restrict__ batch,
                                              float* __restrict__ psum,
                                              float* __restrict__ pcnt, int N) {
    int grp = threadIdx.x >> 7;          // 0/1: alternate rows
    int c = threadIdx.x & 127;
    int n0 = blockIdx.x * 128;
    if (n0 >= N) return;
    int nend = min(n0 + 128, N);
    float acc = 0.0f;
    int run = 0, g = -1;
    for (int n = n0 + grp; n < nend; n += 2) {
        int gn = batch[n];
        if (gn != g) {
            if (run) {
                atomicAdd(&psum[g * HID + c], acc);
                if (c == 0) atomicAdd(&pcnt[g], (float)run);
            }
            acc = 0.0f; run = 0; g = gn;
        }
        acc += H[(size_t)n * HID + c];
        run++;
    }
    if (run) {
        atomicAdd(&psum[g * HID + c], acc);
        if (c == 0) atomicAdd(&pcnt[g], (float)run);
    }
}

__global__ void k_div(const float* __restrict__ psum, const float* __restrict__ pcnt,
                      float* __restrict__ out) {
    int i = blockIdx.x * blockDim.x + threadIdx.x;
    if (i < NGRAPH * HID) out[i] = psum[i] / fmaxf(pcnt[i >> 7], 1.0f);
}

extern "C" void kernel_launch(void* const* d_in, const int* in_sizes, int n_in,
                              void* d_out, int out_size, void* d_ws, size_t ws_size,
                              hipStream_t stream) {
    const float* x     = (const float*)d_in[0];
    const int*   ei    = (const int*)d_in[1];
    const int*   batch = (const int*)d_in[2];
    const float* Ws    = (const float*)d_in[3];
    const float* bs    = (const float*)d_in[4];
    float* out = (float*)d_out;

    int N = in_sizes[2];
    int E = in_sizes[1] / 2;
    const int* esrc = ei;
    const int* edst = ei + E;
    int nblk = (N + 1023) / 1024;        // <= 128 for N <= 131072

    char* w = (char*)d_ws;
    auto alloc = [&](size_t bytes) {
        char* p = w;
        w += (bytes + 255) & ~(size_t)255;
        return p;
    };
    int*    deg    = (int*)   alloc((size_t)N * 4);
    float*  dis    = (float*) alloc((size_t)N * 4);
    int*    rowptr = (int*)   alloc((size_t)(N + 1) * 4);
    int*    cursor = (int*)   alloc((size_t)N * 4);
    int*    bsum   = (int*)   alloc(128 * 4);
    int*    boff   = (int*)   alloc(128 * 4);
    int*    csrc   = (int*)   alloc((size_t)E * 4);
    __half* T      = (__half*)alloc((size_t)N * HID * 2);
    float*  Hb     = (float*) alloc((size_t)N * HID * 4);
    float*  psum   = (float*) alloc((size_t)NGRAPH * HID * 4);
    float*  pcnt   = (float*) alloc((size_t)NGRAPH * 4);

    hipMemsetAsync(deg, 0, (size_t)N * 4, stream);
    hipMemsetAsync(psum, 0, (size_t)NGRAPH * HID * 4, stream);
    hipMemsetAsync(pcnt, 0, (size_t)NGRAPH * 4, stream);

    k_deg      <<<2048, 256, 0, stream>>>(edst, E, deg, N);
    ks_reduce  <<<nblk, 1024, 0, stream>>>(deg, bsum, N);
    ks_scanpart<<<1, 128, 0, stream>>>(bsum, boff, rowptr, nblk, N);
    ks_apply   <<<nblk, 1024, 0, stream>>>(deg, boff, rowptr, cursor, dis, N);
    k_fill     <<<2048, 256, 0, stream>>>(esrc, edst, E, cursor, csrc, N);

    const float* hin = x;
    for (int l = 0; l < NLAYER; ++l) {
        k_gemm<<<(N + 63) / 64, 256, 0, stream>>>(hin, Ws + (size_t)l * HID * HID, dis, T, N);
        k_agg <<<(N + 3) / 4, 256, 0, stream>>>(T, Hb, rowptr, csrc, dis,
                                                bs + (size_t)l * HID, N);
        hin = Hb;
    }
    k_pool<<<(N + 127) / 128, 256, 0, stream>>>(Hb, batch, psum, pcnt, N);
    k_div <<<(NGRAPH * HID + 255) / 256, 256, 0, stream>>>(psum, pcnt, out);
}

// Round 13
// 665.723 us; speedup vs baseline: 1.7792x; 1.0558x over previous
//
#include <hip/hip_runtime.h>
#include <hip/hip_fp16.h>

#define HID 128
#define NLAYER 3
#define NGRAPH 64
#define NPART 8          // one dst-range per XCD (blockIdx % 8 ~ XCD round-robin)

// ---------- degree histogram, XCD-partitioned by dst range ----------
__global__ void __launch_bounds__(256) k_deg(const int* __restrict__ dst, int E,
                                             int* __restrict__ deg, int N) {
    int part = blockIdx.x & (NPART - 1);
    int grp  = blockIdx.x >> 3;
    int ngrp = gridDim.x >> 3;
    int lo = (int)((long long)part * N / NPART);
    int hi = (int)((long long)(part + 1) * N / NPART);
    for (int e = grp * 256 + threadIdx.x; e < E; e += ngrp * 256) {
        int d = dst[e];
        if (d >= lo && d < hi) atomicAdd(&deg[d], 1);
    }
}

// ---------- 3-phase parallel exclusive scan of deg -> rowptr, cursor, dis ----------
__global__ void __launch_bounds__(1024) ks_reduce(const int* __restrict__ deg,
                                                  int* __restrict__ bsum, int N) {
    __shared__ int ws[16];
    int i = blockIdx.x * 1024 + threadIdx.x;
    int v = (i < N) ? deg[i] : 0;
    #pragma unroll
    for (int d = 32; d > 0; d >>= 1) v += __shfl_down(v, d, 64);
    int lane = threadIdx.x & 63, wid = threadIdx.x >> 6;
    if (lane == 0) ws[wid] = v;
    __syncthreads();
    if (threadIdx.x == 0) {
        int s = 0;
        #pragma unroll
        for (int j = 0; j < 16; ++j) s += ws[j];
        bsum[blockIdx.x] = s;
    }
}

__global__ void __launch_bounds__(128) ks_scanpart(const int* __restrict__ bsum,
                                                   int* __restrict__ boff,
                                                   int* __restrict__ rowptr,
                                                   int nblk, int N) {
    __shared__ int w0sum;
    int tid = threadIdx.x;
    int v = (tid < nblk) ? bsum[tid] : 0;
    int x = v;
    #pragma unroll
    for (int d = 1; d < 64; d <<= 1) {
        int t = __shfl_up(x, d, 64);
        if ((tid & 63) >= d) x += t;
    }
    if (tid == 63) w0sum = x;
    __syncthreads();
    if (tid >= 64) x += w0sum;
    if (tid < nblk) boff[tid] = x - v;
    if (tid == nblk - 1) rowptr[N] = x;
}

__global__ void __launch_bounds__(1024) ks_apply(const int* __restrict__ deg,
                                                 const int* __restrict__ boff,
                                                 int* __restrict__ rowptr,
                                                 int* __restrict__ cursor,
                                                 float* __restrict__ dis, int N) {
    __shared__ int wsum[17];
    int tid = threadIdx.x;
    int lane = tid & 63, wid = tid >> 6;
    int i = blockIdx.x * 1024 + tid;
    int v = (i < N) ? deg[i] : 0;
    int x = v;
    #pragma unroll
    for (int d = 1; d < 64; d <<= 1) {
        int t = __shfl_up(x, d, 64);
        if (lane >= d) x += t;
    }
    if (lane == 63) wsum[wid] = x;
    __syncthreads();
    if (tid == 0) {
        int run = 0;
        #pragma unroll
        for (int j = 0; j < 16; ++j) { int t = wsum[j]; wsum[j] = run; run += t; }
    }
    __syncthreads();
    if (i < N) {
        int excl = boff[blockIdx.x] + wsum[wid] + x - v;
        rowptr[i] = excl;
        cursor[i] = excl;
        dis[i] = rsqrtf((float)v + 1.0f);   // +1 = self-loop
    }
}

// ---------- CSR fill, XCD-partitioned by dst range ----------
__global__ void __launch_bounds__(256) k_fill(const int* __restrict__ src,
                                              const int* __restrict__ dst, int E,
                                              int* __restrict__ cursor,
                                              int* __restrict__ csrc, int N) {
    int part = blockIdx.x & (NPART - 1);
    int grp  = blockIdx.x >> 3;
    int ngrp = gridDim.x >> 3;
    int lo = (int)((long long)part * N / NPART);
    int hi = (int)((long long)(part + 1) * N / NPART);
    for (int e = grp * 256 + threadIdx.x; e < E; e += ngrp * 256) {
        int d = dst[e];
        if (d >= lo && d < hi) {
            int pos = atomicAdd(&cursor[d], 1);
            csrc[pos] = src[e];
        }
    }
}

// ---------- T' = fp16( dis[n] * (A @ W)[n] )  (K-tiled: 32 KiB LDS -> 5 blocks/CU) ----------
__global__ void __launch_bounds__(256) k_gemm(const float* __restrict__ A,
                                              const float* __restrict__ W,
                                              const float* __restrict__ dis,
                                              __half* __restrict__ T, int N) {
    __shared__ float sW[64 * HID];   // 32 KiB: one 64-row K-tile of W
    int c4 = (threadIdx.x & 31) * 4;     // 4 output cols
    int rb = threadIdx.x >> 5;           // 0..7
    int row0 = blockIdx.x * 64;

    int r[8]; const float* a[8];
    #pragma unroll
    for (int j = 0; j < 8; ++j) {
        r[j] = row0 + rb + 8 * j;
        a[j] = A + (size_t)min(r[j], N - 1) * HID;
    }

    float4 acc[8];
    #pragma unroll
    for (int j = 0; j < 8; ++j) acc[j] = float4{0, 0, 0, 0};

    for (int k0 = 0; k0 < HID; k0 += 64) {
        __syncthreads();   // all reads of previous tile done before overwrite
        for (int i = threadIdx.x; i < 64 * HID / 4; i += 256)
            ((float4*)sW)[i] = ((const float4*)(W + (size_t)k0 * HID))[i];
        __syncthreads();

        for (int k = 0; k < 64; k += 4) {
            float4 va[8];
            #pragma unroll
            for (int j = 0; j < 8; ++j) va[j] = *(const float4*)(a[j] + k0 + k);
            #pragma unroll
            for (int kk = 0; kk < 4; ++kk) {
                float4 w = *(const float4*)&sW[(k + kk) * HID + c4];
                #pragma unroll
                for (int j = 0; j < 8; ++j) {
                    float e = (&va[j].x)[kk];
                    acc[j].x += e * w.x; acc[j].y += e * w.y;
                    acc[j].z += e * w.z; acc[j].w += e * w.w;
                }
            }
        }
    }
    #pragma unroll
    for (int j = 0; j < 8; ++j) {
        if (r[j] < N) {
            float d = dis[r[j]];
            ushort4 u;
            u.x = __half_as_ushort(__float2half_rn(acc[j].x * d));
            u.y = __half_as_ushort(__float2half_rn(acc[j].y * d));
            u.z = __half_as_ushort(__float2half_rn(acc[j].z * d));
            u.w = __half_as_ushort(__float2half_rn(acc[j].w * d));
            *(ushort4*)((unsigned short*)T + (size_t)r[j] * HID + c4) = u;
        }
    }
}

// ---------- aggregation: one wave per node, half2/lane (256B row per instr) ----------
// H[n] = relu(bias + dis[n] * (T'[n] + sum_e T'[src_e]))
__global__ void __launch_bounds__(256) k_agg(const __half* __restrict__ Tp,
                                             float* __restrict__ H,
                                             const int* __restrict__ rowptr,
                                             const int* __restrict__ csrc,
                                             const float* __restrict__ dis,
                                             const float* __restrict__ bias, int N) {
    int n = blockIdx.x * 4 + (threadIdx.x >> 6);
    int lane = threadIdx.x & 63;
    if (n >= N) return;

    const __half2* base = (const __half2*)Tp;   // row stride = 64 half2
    float2 selfv = __half22float2(base[(size_t)n * 64 + lane]);
    float2 acc  = selfv;
    float2 acc2 = {0.0f, 0.0f};
    int e = rowptr[n], e1 = rowptr[n + 1];

    for (; e + 7 < e1; e += 8) {
        int s0 = csrc[e],     s1 = csrc[e + 1], s2 = csrc[e + 2], s3 = csrc[e + 3];
        int s4 = csrc[e + 4], s5 = csrc[e + 5], s6 = csrc[e + 6], s7 = csrc[e + 7];
        __half2 h0 = base[(size_t)s0 * 64 + lane];
        __half2 h1 = base[(size_t)s1 * 64 + lane];
        __half2 h2 = base[(size_t)s2 * 64 + lane];
        __half2 h3 = base[(size_t)s3 * 64 + lane];
        __half2 h4 = base[(size_t)s4 * 64 + lane];
        __half2 h5 = base[(size_t)s5 * 64 + lane];
        __half2 h6 = base[(size_t)s6 * 64 + lane];
        __half2 h7 = base[(size_t)s7 * 64 + lane];
        float2 v0 = __half22float2(h0), v1 = __half22float2(h1);
        float2 v2 = __half22float2(h2), v3 = __half22float2(h3);
        float2 v4 = __half22float2(h4), v5 = __half22float2(h5);
        float2 v6 = __half22float2(h6), v7 = __half22float2(h7);
        acc.x  += v0.x + v1.x + v2.x + v3.x;
        acc.y  += v0.y + v1.y + v2.y + v3.y;
        acc2.x += v4.x + v5.x + v6.x + v7.x;
        acc2.y += v4.y + v5.y + v6.y + v7.y;
    }
    for (; e + 1 < e1; e += 2) {
        int s0 = csrc[e], s1 = csrc[e + 1];
        float2 v0 = __half22float2(base[(size_t)s0 * 64 + lane]);
        float2 v1 = __half22float2(base[(size_t)s1 * 64 + lane]);
        acc.x += v0.x + v1.x;
        acc.y += v0.y + v1.y;
    }
    if (e < e1) {
        float2 v = __half22float2(base[(size_t)csrc[e] * 64 + lane]);
        acc.x += v.x; acc.y += v.y;
    }
    acc.x += acc2.x; acc.y += acc2.y;

    float dn = dis[n];
    float2 b2 = ((const float2*)bias)[lane];
    float2 rr;
    rr.x = fmaxf(b2.x + dn * acc.x, 0.0f);
    rr.y = fmaxf(b2.y + dn * acc.y, 0.0f);
    ((float2*)H)[(size_t)n * 64 + lane] = rr;
}

// ---------- pooling: run-length local sums, 2 interleaved row groups ----------
__global__ void __launch_bounds__(256) k_pool(const float* __restrict__ H,
                                              const int* __restrict__ batch,
                                              float* __restrict__ psum,
                                              float* __restrict__ pcnt, int N) {
    int grp = threadIdx.x >> 7;          // 0/1: alternate rows
    int c = threadIdx.x & 127;
    int n0 = blockIdx.x * 128;
    if (n0 >= N) return;
    int nend = min(n0 + 128, N);
    float acc = 0.0f;
    int run = 0, g = -1;
    for (int n = n0 + grp; n < nend; n += 2) {
        int gn = batch[n];
        if (gn != g) {
            if (run) {
                atomicAdd(&psum[g * HID + c], acc);
                if (c == 0) atomicAdd(&pcnt[g], (float)run);
            }
            acc = 0.0f; run = 0; g = gn;
        }
        acc += H[(size_t)n * HID + c];
        run++;
    }
    if (run) {
        atomicAdd(&psum[g * HID + c], acc);
        if (c == 0) atomicAdd(&pcnt[g], (float)run);
    }
}

__global__ void k_div(const float* __restrict__ psum, const float* __restrict__ pcnt,
                      float* __restrict__ out) {
    int i = blockIdx.x * blockDim.x + threadIdx.x;
    if (i < NGRAPH * HID) out[i] = psum[i] / fmaxf(pcnt[i >> 7], 1.0f);
}

extern "C" void kernel_launch(void* const* d_in, const int* in_sizes, int n_in,
                              void* d_out, int out_size, void* d_ws, size_t ws_size,
                              hipStream_t stream) {
    const float* x     = (const float*)d_in[0];
    const int*   ei    = (const int*)d_in[1];
    const int*   batch = (const int*)d_in[2];
    const float* Ws    = (const float*)d_in[3];
    const float* bs    = (const float*)d_in[4];
    float* out = (float*)d_out;

    int N = in_sizes[2];
    int E = in_sizes[1] / 2;
    const int* esrc = ei;
    const int* edst = ei + E;
    int nblk = (N + 1023) / 1024;        // <= 128 for N <= 131072

    char* w = (char*)d_ws;
    auto alloc = [&](size_t bytes) {
        char* p = w;
        w += (bytes + 255) & ~(size_t)255;
        return p;
    };
    int*    deg    = (int*)   alloc((size_t)N * 4);
    float*  dis    = (float*) alloc((size_t)N * 4);
    int*    rowptr = (int*)   alloc((size_t)(N + 1) * 4);
    int*    cursor = (int*)   alloc((size_t)N * 4);
    int*    bsum   = (int*)   alloc(128 * 4);
    int*    boff   = (int*)   alloc(128 * 4);
    int*    csrc   = (int*)   alloc((size_t)E * 4);
    __half* T      = (__half*)alloc((size_t)N * HID * 2);
    float*  Hb     = (float*) alloc((size_t)N * HID * 4);
    float*  psum   = (float*) alloc((size_t)NGRAPH * HID * 4);
    float*  pcnt   = (float*) alloc((size_t)NGRAPH * 4);

    hipMemsetAsync(deg, 0, (size_t)N * 4, stream);
    hipMemsetAsync(psum, 0, (size_t)NGRAPH * HID * 4, stream);
    hipMemsetAsync(pcnt, 0, (size_t)NGRAPH * 4, stream);

    k_deg      <<<2048, 256, 0, stream>>>(edst, E, deg, N);
    ks_reduce  <<<nblk, 1024, 0, stream>>>(deg, bsum, N);
    ks_scanpart<<<1, 128, 0, stream>>>(bsum, boff, rowptr, nblk, N);
    ks_apply   <<<nblk, 1024, 0, stream>>>(deg, boff, rowptr, cursor, dis, N);
    k_fill     <<<2048, 256, 0, stream>>>(esrc, edst, E, cursor, csrc, N);

    const float* hin = x;
    for (int l = 0; l < NLAYER; ++l) {
        k_gemm<<<(N + 63) / 64, 256, 0, stream>>>(hin, Ws + (size_t)l * HID * HID, dis, T, N);
        k_agg <<<(N + 3) / 4, 256, 0, stream>>>(T, Hb, rowptr, csrc, dis,
                                                bs + (size_t)l * HID, N);
        hin = Hb;
    }
    k_pool<<<(N + 127) / 128, 256, 0, stream>>>(Hb, batch, psum, pcnt, N);
    k_div <<<(NGRAPH * HID + 255) / 256, 256, 0, stream>>>(psum, pcnt, out);
}